// Round 13
// baseline (124.806 us; speedup 1.0000x reference)
//
#include <hip/hip_runtime.h>

#define N_NODES 50000
#define N_EDGES 800000
#define DIM 100

#define SB_COUNT 98         // super-buckets of 512 nodes (dst>>9)
#define CAP1     8704       // records per super-bucket region (mean 8163, +6 sigma)
#define OVF_CAP  4096
#define EPB1     2048       // edges per bin1 block -> 391 bin1 blocks
#define BIN1_BLOCKS 391
#define GEMM_BLOCKS 1250    // 50000/40
#define ROWS_PB  40
#define SPLITA   8          // agg blocks per super-bucket (64 nodes each)
#define SRT_CAP  2048       // records per 64-node chunk (mean 1024, +32 sigma)

// ---------------- workspace layout (bytes) ----------------
#define HIDB_OFF  0u            // bf16 hidden, packed uint[50000*50]   10,000,000
#define G1_OFF    10000000u     // int gcur1[98]
#define OVFC_OFF  10000448u     // int ovf_cnt
#define OVF_OFF   10000464u     // int4 ovf[4096] (16B-aligned)             65,536
#define BKT1_OFF  10066048u     // uint2 bkt1[98*8704] (128B-aligned)    6,823,936
#define WT_OFF    16889984u     // float Wt[100*100]                        40,000
#define WS_NEED   16929984u

// float->bf16 RNE helpers
__device__ inline unsigned bf16hi(float v) {            // bf16 in HIGH 16 bits
    unsigned u = __float_as_uint(v);
    u += 0x7FFFu + ((u >> 16) & 1u);
    return u & 0xFFFF0000u;
}
__device__ inline unsigned bf16pair(float lo, float hi) {
    unsigned ulo = __float_as_uint(lo); ulo += 0x7FFFu + ((ulo >> 16) & 1u);
    unsigned uhi = __float_as_uint(hi); uhi += 0x7FFFu + ((uhi >> 16) & 1u);
    return (ulo >> 16) | (uhi & 0xFFFF0000u);
}

// ---------------- transpose + control-buffer zeroing ----------------
__global__ __launch_bounds__(256) void srgnn_transpose(
    const float* __restrict__ W, float* __restrict__ Wt,
    int* __restrict__ gcur1, int* __restrict__ ovfc)
{
    const unsigned i = blockIdx.x * 256u + threadIdx.x;
    if (i < DIM * DIM) {
        const int c = i / DIM, k = i - c * DIM;
        Wt[k * DIM + c] = W[i];
    }
    if (i < SB_COUNT) gcur1[i] = 0;
    if (i == 0) *ovfc = 0;
}

// ---------------- GEMM: hidden(bf16) = x @ W^T + b -----------------------
// Wt staged in LDS (40KB, straight coalesced copy -> conflict-free) so the
// 100-iter inner loop touches NO global memory (old version thrashed L1:
// 40KB Wt > 32KB L1 -> perpetual L2-latency stalls, VALUBusy 31%).
// 56KB LDS -> 2 blocks/CU; unroll-4 ILP covers LDS latency.
__global__ __launch_bounds__(256, 2) void srgnn_gemm3(
    const float* __restrict__ x, const float* __restrict__ Wtg,
    const float* __restrict__ b, unsigned* __restrict__ hidU)
{
    __shared__ float Wt[DIM][DIM];       // 40000 B, Wt[k][c]
    __shared__ float xs[ROWS_PB][DIM];   // 16000 B
    const int t = threadIdx.x;
    const int row0 = blockIdx.x * ROWS_PB;

    // stage Wt: straight copy (coalesced float4 load + conflict-free store)
    for (int i = t; i < 2500; i += 256) {
        const float4 v = *reinterpret_cast<const float4*>(&Wtg[i * 4]);
        *reinterpret_cast<float4*>(&Wt[0][0] + i * 4) = v;
    }
    // stage x rows
    for (int i = t; i < ROWS_PB * 25; i += 256) {
        const int r = i / 25, c4 = (i - r * 25) * 4;
        const float4 v = *reinterpret_cast<const float4*>(
            &x[(size_t)(row0 + r) * DIM + c4]);
        *reinterpret_cast<float4*>(&xs[r][c4]) = v;
    }
    __syncthreads();

    if (t < 250) {
        const int g  = t / 25;            // row group 0..9
        const int c4 = (t - g * 25) * 4;  // col chunk
        const float4 bv = *reinterpret_cast<const float4*>(&b[c4]);
        float4 a0 = bv, a1 = bv, a2 = bv, a3 = bv;

        #pragma unroll 4
        for (int k = 0; k < DIM; ++k) {
            const float4 wv = *reinterpret_cast<const float4*>(&Wt[k][c4]);
            const float x0 = xs[g     ][k];
            const float x1 = xs[g + 10][k];
            const float x2 = xs[g + 20][k];
            const float x3 = xs[g + 30][k];
            a0.x += x0 * wv.x; a0.y += x0 * wv.y; a0.z += x0 * wv.z; a0.w += x0 * wv.w;
            a1.x += x1 * wv.x; a1.y += x1 * wv.y; a1.z += x1 * wv.z; a1.w += x1 * wv.w;
            a2.x += x2 * wv.x; a2.y += x2 * wv.y; a2.z += x2 * wv.z; a2.w += x2 * wv.w;
            a3.x += x3 * wv.x; a3.y += x3 * wv.y; a3.z += x3 * wv.z; a3.w += x3 * wv.w;
        }
        const int u0 = c4 >> 1;           // uint index within row (50/row)
        uint2 p;
        p.x = bf16pair(a0.x, a0.y); p.y = bf16pair(a0.z, a0.w);
        *reinterpret_cast<uint2*>(&hidU[(size_t)(row0 + g     ) * 50 + u0]) = p;
        p.x = bf16pair(a1.x, a1.y); p.y = bf16pair(a1.z, a1.w);
        *reinterpret_cast<uint2*>(&hidU[(size_t)(row0 + g + 10) * 50 + u0]) = p;
        p.x = bf16pair(a2.x, a2.y); p.y = bf16pair(a2.z, a2.w);
        *reinterpret_cast<uint2*>(&hidU[(size_t)(row0 + g + 20) * 50 + u0]) = p;
        p.x = bf16pair(a3.x, a3.y); p.y = bf16pair(a3.z, a3.w);
        *reinterpret_cast<uint2*>(&hidU[(size_t)(row0 + g + 30) * 50 + u0]) = p;
    }
}

// ---------------- bin1: edges -> 98 super-buckets of 512 nodes ------------
// Runs of ~21 records per (block,SB): stores dense & temporally local.
__global__ __launch_bounds__(256) void srgnn_bin1(
    const int* __restrict__ esrc, const int* __restrict__ edst,
    const float* __restrict__ ew, int* __restrict__ gcur1,
    int* __restrict__ ovfc, int4* __restrict__ ovf, uint2* __restrict__ bkt1)
{
    __shared__ int hist[SB_COUNT];
    __shared__ int lcur[SB_COUNT];
    const int t = threadIdx.x;
    const int e0 = blockIdx.x * EPB1;

    for (int i = t; i < SB_COUNT; i += 256) hist[i] = 0;
    __syncthreads();

    int d[8];
    #pragma unroll
    for (int k = 0; k < 8; ++k) {
        const int e = e0 + t + k * 256;
        d[k] = (e < N_EDGES) ? edst[e] : -1;
        if (d[k] >= 0) atomicAdd(&hist[d[k] >> 9], 1);
    }
    __syncthreads();
    for (int i = t; i < SB_COUNT; i += 256)
        if (hist[i]) lcur[i] = atomicAdd(&gcur1[i], hist[i]);
    __syncthreads();
    #pragma unroll
    for (int k = 0; k < 8; ++k) {
        if (d[k] >= 0) {
            const int e = e0 + t + k * 256;
            const int s = esrc[e];
            const float w = ew[e];
            const int sb = d[k] >> 9;
            const int pos = atomicAdd(&lcur[sb], 1);
            if (pos < CAP1) {
                bkt1[(size_t)sb * CAP1 + pos] =
                    make_uint2((unsigned)s | bf16hi(w), (unsigned)d[k]);
            } else {
                const int op = atomicAdd(ovfc, 1);
                if (op < OVF_CAP) ovf[op] = make_int4(d[k], s, __float_as_int(w), 0);
            }
        }
    }
}

// ---------------- aggregate: 8 blocks per super-bucket --------------------
// Block (sb,chunk) owns nodes sb*512+chunk*64..+63. Two coalesced passes
// over the SB's contiguous bkt1 region (L2-resident): hist its 64 nodes,
// scan, place into LDS srt. Then wave-per-node x16: LDS broadcast records,
// bf16 row gathers 8-deep, f32 accumulate, plain float2 store. Replaces
// bin2's global round-trip with cheap redundant L2 reads.
__global__ __launch_bounds__(256) void srgnn_agg_sb(
    const unsigned* __restrict__ hidU, const int* __restrict__ gcur1,
    const uint2* __restrict__ bkt1, const int* __restrict__ ovfc,
    const int4* __restrict__ ovf, float* __restrict__ out)
{
    __shared__ unsigned srt[SRT_CAP];    // 8192 B
    __shared__ int nh[64], sc[64], cur[64];

    const int t = threadIdx.x;
    const int sb = blockIdx.x >> 3;
    const int chunk = blockIdx.x & 7;
    const unsigned key = (unsigned)chunk;

    int cnt = gcur1[sb];
    if (cnt > CAP1) cnt = CAP1;

    if (t < 64) nh[t] = 0;
    __syncthreads();

    // pass 1: count my 64 nodes
    for (int i = t; i < cnt; i += 256) {
        const uint2 r = bkt1[(size_t)sb * CAP1 + i];
        if (((r.y >> 6) & 7u) == key) atomicAdd(&nh[r.y & 63], 1);
    }
    __syncthreads();
    if (t < 64) sc[t] = nh[t];
    __syncthreads();
    for (int ofs = 1; ofs < 64; ofs <<= 1) {         // Hillis-Steele inclusive
        int a = 0;
        if (t < 64 && t >= ofs) a = sc[t - ofs];
        __syncthreads();
        if (t < 64) sc[t] += a;
        __syncthreads();
    }
    if (t < 64) cur[t] = sc[t] - nh[t];
    __syncthreads();

    // pass 2: place my records into LDS, grouped by node
    for (int i = t; i < cnt; i += 256) {
        const uint2 r = bkt1[(size_t)sb * CAP1 + i];
        if (((r.y >> 6) & 7u) == key) {
            const int pos = atomicAdd(&cur[r.y & 63], 1);
            if (pos < SRT_CAP) srt[pos] = r.x;       // src | bf16(w)<<16
        }
    }
    __syncthreads();

    int oc = *ovfc;                                  // ~always 0
    if (oc > OVF_CAP) oc = OVF_CAP;
    const int lane = t & 63;
    const int wid  = t >> 6;                         // 4 waves
    const bool active = (lane < 50);

    for (int q = 0; q < 16; ++q) {
        const int n  = wid * 16 + q;                 // 4 waves x 16 = 64 nodes
        const int s1 = sc[n];
        const int s0 = s1 - nh[n];
        float2 acc = make_float2(0.f, 0.f);

        int p = s0;
        for (; p + 8 <= s1; p += 8) {                // 8-deep MLP
            unsigned r[8], h[8];
            #pragma unroll
            for (int j = 0; j < 8; ++j) r[j] = srt[p + j];
            if (active) {
                #pragma unroll
                for (int j = 0; j < 8; ++j)
                    h[j] = hidU[(size_t)(r[j] & 0xFFFFu) * 50 + lane];
                #pragma unroll
                for (int j = 0; j < 8; ++j) {
                    const float wj = __uint_as_float(r[j] & 0xFFFF0000u);
                    acc.x += wj * __uint_as_float(h[j] << 16);
                    acc.y += wj * __uint_as_float(h[j] & 0xFFFF0000u);
                }
            }
        }
        for (; p < s1; ++p) {
            const unsigned r = srt[p];
            const float wi = __uint_as_float(r & 0xFFFF0000u);
            if (active) {
                const unsigned h = hidU[(size_t)(r & 0xFFFFu) * 50 + lane];
                acc.x += wi * __uint_as_float(h << 16);
                acc.y += wi * __uint_as_float(h & 0xFFFF0000u);
            }
        }

        const int ng = sb * 512 + chunk * 64 + n;
        if (oc > 0) {                                // ultra-rare overflow scan
            for (int i = 0; i < oc; ++i) {
                const int4 v = ovf[i];
                if (v.x == ng && active) {
                    const unsigned h = hidU[(size_t)v.y * 50 + lane];
                    const float wi = __int_as_float(v.z);
                    acc.x += wi * __uint_as_float(h << 16);
                    acc.y += wi * __uint_as_float(h & 0xFFFF0000u);
                }
            }
        }
        if (ng < N_NODES && active)
            *reinterpret_cast<float2*>(&out[(size_t)ng * DIM + 2 * lane]) = acc;
    }
}

// ---------------- fallback (atomic scatter, needs only 20MB ws) ----------
__global__ __launch_bounds__(256) void srgnn_gemm_bias(
    const float* __restrict__ x, const float* __restrict__ W,
    const float* __restrict__ b, float* __restrict__ hidden)
{
    __shared__ float Wt[DIM][DIM + 4];
    __shared__ float bs[DIM];
    __shared__ float xs[8][DIM];
    const int t = threadIdx.x;
    for (int i = t; i < DIM * DIM; i += 256) {
        int c = i / DIM, k = i - c * DIM;
        Wt[k][c] = W[i];
    }
    if (t < DIM) bs[t] = b[t];
    const int row0 = blockIdx.x * 8;
    for (int i = t; i < 8 * DIM; i += 256) {
        int r = i / DIM, k = i - r * DIM;
        int row = row0 + r;
        xs[r][k] = (row < N_NODES) ? x[row * DIM + k] : 0.0f;
    }
    __syncthreads();
    if (t < 200) {
        const int r  = t / 25;
        const int c4 = (t - r * 25) * 4;
        float acc0 = bs[c4 + 0], acc1 = bs[c4 + 1], acc2 = bs[c4 + 2], acc3 = bs[c4 + 3];
        for (int k = 0; k < DIM; ++k) {
            const float xv = xs[r][k];
            const float4 wv = *reinterpret_cast<const float4*>(&Wt[k][c4]);
            acc0 += xv * wv.x; acc1 += xv * wv.y; acc2 += xv * wv.z; acc3 += xv * wv.w;
        }
        const int row = row0 + r;
        if (row < N_NODES)
            *reinterpret_cast<float4*>(&hidden[row * DIM + c4]) =
                make_float4(acc0, acc1, acc2, acc3);
    }
}

__global__ __launch_bounds__(256) void srgnn_scatter_atomic(
    const float* __restrict__ hidden, const int* __restrict__ esrc,
    const int* __restrict__ edst, const float* __restrict__ ew,
    float* __restrict__ out)
{
    const unsigned gid = blockIdx.x * 256u + threadIdx.x;
    const unsigned e = gid / 25u;
    const unsigned j = gid - e * 25u;
    if (e >= N_EDGES) return;
    const int   s  = esrc[e];
    const int   d  = edst[e];
    const float wt = ew[e];
    const float4 h = *reinterpret_cast<const float4*>(&hidden[(size_t)s * DIM + j * 4]);
    float* op = &out[(size_t)d * DIM + j * 4];
    atomicAdd(op + 0, h.x * wt);
    atomicAdd(op + 1, h.y * wt);
    atomicAdd(op + 2, h.z * wt);
    atomicAdd(op + 3, h.w * wt);
}

extern "C" void kernel_launch(void* const* d_in, const int* in_sizes, int n_in,
                              void* d_out, int out_size, void* d_ws, size_t ws_size,
                              hipStream_t stream) {
    const float* x    = (const float*)d_in[0];
    const int*   esrc = (const int*)  d_in[1];
    const int*   edst = (const int*)  d_in[2];
    const float* ew   = (const float*)d_in[3];
    const float* W    = (const float*)d_in[4];
    const float* b    = (const float*)d_in[5];
    float* out = (float*)d_out;

    char* ws = (char*)d_ws;

    if (ws_size >= WS_NEED) {
        unsigned* hidU  = (unsigned*)(ws + HIDB_OFF);
        int*      gcur1 = (int*)     (ws + G1_OFF);
        int*      ovfc  = (int*)     (ws + OVFC_OFF);
        int4*     ovf   = (int4*)    (ws + OVF_OFF);
        uint2*    bkt1  = (uint2*)   (ws + BKT1_OFF);
        float*    Wt    = (float*)   (ws + WT_OFF);

        // transpose W + zero control buffers
        srgnn_transpose<<<(DIM * DIM + 255) / 256, 256, 0, stream>>>(
            W, Wt, gcur1, ovfc);
        // GEMM with LDS-resident Wt
        srgnn_gemm3<<<GEMM_BLOCKS, 256, 0, stream>>>(x, Wt, b, hidU);
        // bin edges into 98 super-buckets (contiguous runs)
        srgnn_bin1<<<BIN1_BLOCKS, 256, 0, stream>>>(
            esrc, edst, ew, gcur1, ovfc, ovf, bkt1);
        // aggregate: 8 blocks/super-bucket, LDS filter+sort + gather
        srgnn_agg_sb<<<SB_COUNT * SPLITA, 256, 0, stream>>>(
            hidU, gcur1, bkt1, ovfc, ovf, out);
    } else {
        // fallback: atomic scatter
        float* hidden = (float*)ws;
        hipMemsetAsync(d_out, 0, (size_t)out_size * sizeof(float), stream);
        const int gemm_blocks = (N_NODES + 7) / 8;
        srgnn_gemm_bias<<<gemm_blocks, 256, 0, stream>>>(x, W, b, hidden);
        const long long work = (long long)N_EDGES * 25;
        const int scat_blocks = (int)((work + 255) / 256);
        srgnn_scatter_atomic<<<scat_blocks, 256, 0, stream>>>(hidden, esrc, edst, ew, out);
    }
}

// Round 14
// 94.278 us; speedup vs baseline: 1.3238x; 1.3238x over previous
//
#include <hip/hip_runtime.h>

#define N_NODES 50000
#define N_EDGES 800000
#define DIM 100

#define SB_COUNT 98         // super-buckets of 512 nodes (dst>>9)
#define CAP1     8704       // records per super-bucket region (mean 8163, +6 sigma)
#define NB       1563       // final buckets of 32 nodes (dst>>5)
#define CAPB     768        // records per final bucket (mean 512, +11 sigma)
#define OVF_CAP  4096
#define EPB1     2048       // edges per bin1 block -> 391 bin1 blocks
#define BIN1_BLOCKS 391
#define GEMM_BLOCKS 1250    // 50000/40
#define ROWS_PB  40
#define SPLIT2   8          // bin2 blocks per super-bucket -> 784 blocks

// ---------------- workspace layout (bytes) ----------------
#define HIDB_OFF  0u            // bf16 hidden, packed uint[50000*50]   10,000,000
#define G1_OFF    10000000u     // int gcur1[98]
#define OVFC_OFF  10000448u     // int ovf_cnt
#define CNT2_OFF  10000512u     // int cnt2[1568] (cursor == final count)
#define CNT2_END  10006784u
#define OVF_OFF   10006784u     // int4 ovf[4096] (16B-aligned)             65,536
#define BKT1_OFF  10072320u     // uint2 bkt1[98*8704] (128B-aligned)    6,823,936
#define BKT2_OFF  16896256u     // uint2 bkt2[1568*768]                  9,633,792
#define WT_OFF    26530048u     // float Wt[100*100]                        40,000
#define WS_NEED   26570048u

// float->bf16 RNE helpers
__device__ inline unsigned bf16hi(float v) {            // bf16 in HIGH 16 bits
    unsigned u = __float_as_uint(v);
    u += 0x7FFFu + ((u >> 16) & 1u);
    return u & 0xFFFF0000u;
}
__device__ inline unsigned bf16pair(float lo, float hi) {
    unsigned ulo = __float_as_uint(lo); ulo += 0x7FFFu + ((ulo >> 16) & 1u);
    unsigned uhi = __float_as_uint(hi); uhi += 0x7FFFu + ((uhi >> 16) & 1u);
    return (ulo >> 16) | (uhi & 0xFFFF0000u);
}

// ---------------- transpose + control-buffer zeroing ----------------
__global__ __launch_bounds__(256) void srgnn_transpose(
    const float* __restrict__ W, float* __restrict__ Wt,
    int* __restrict__ gcur1, int* __restrict__ cnt2, int* __restrict__ ovfc)
{
    const unsigned i = blockIdx.x * 256u + threadIdx.x;
    if (i < DIM * DIM) {
        const int c = i / DIM, k = i - c * DIM;
        Wt[k * DIM + c] = W[i];
    }
    if (i < SB_COUNT) gcur1[i] = 0;
    if (i < SB_COUNT * 16) cnt2[i] = 0;
    if (i == 0) *ovfc = 0;
}

// ---------------- GEMM: hidden(bf16) = x @ W^T + b -----------------------
// Wt staged in LDS (40KB): the 100-iter inner loop touches NO global
// memory. (The global-Wt version thrashed L1 - 40KB > 32KB - and ran at
// ~33us, VALUBusy 31%.) 56KB LDS -> 2 blocks/CU.
__global__ __launch_bounds__(256, 2) void srgnn_gemm3(
    const float* __restrict__ x, const float* __restrict__ Wtg,
    const float* __restrict__ b, unsigned* __restrict__ hidU)
{
    __shared__ float Wt[DIM][DIM];       // 40000 B, Wt[k][c]
    __shared__ float xs[ROWS_PB][DIM];   // 16000 B
    const int t = threadIdx.x;
    const int row0 = blockIdx.x * ROWS_PB;

    for (int i = t; i < 2500; i += 256) {
        const float4 v = *reinterpret_cast<const float4*>(&Wtg[i * 4]);
        *reinterpret_cast<float4*>(&Wt[0][0] + i * 4) = v;
    }
    for (int i = t; i < ROWS_PB * 25; i += 256) {
        const int r = i / 25, c4 = (i - r * 25) * 4;
        const float4 v = *reinterpret_cast<const float4*>(
            &x[(size_t)(row0 + r) * DIM + c4]);
        *reinterpret_cast<float4*>(&xs[r][c4]) = v;
    }
    __syncthreads();

    if (t < 250) {
        const int g  = t / 25;            // row group 0..9
        const int c4 = (t - g * 25) * 4;  // col chunk
        const float4 bv = *reinterpret_cast<const float4*>(&b[c4]);
        float4 a0 = bv, a1 = bv, a2 = bv, a3 = bv;

        #pragma unroll 4
        for (int k = 0; k < DIM; ++k) {
            const float4 wv = *reinterpret_cast<const float4*>(&Wt[k][c4]);
            const float x0 = xs[g     ][k];
            const float x1 = xs[g + 10][k];
            const float x2 = xs[g + 20][k];
            const float x3 = xs[g + 30][k];
            a0.x += x0 * wv.x; a0.y += x0 * wv.y; a0.z += x0 * wv.z; a0.w += x0 * wv.w;
            a1.x += x1 * wv.x; a1.y += x1 * wv.y; a1.z += x1 * wv.z; a1.w += x1 * wv.w;
            a2.x += x2 * wv.x; a2.y += x2 * wv.y; a2.z += x2 * wv.z; a2.w += x2 * wv.w;
            a3.x += x3 * wv.x; a3.y += x3 * wv.y; a3.z += x3 * wv.z; a3.w += x3 * wv.w;
        }
        const int u0 = c4 >> 1;           // uint index within row (50/row)
        uint2 p;
        p.x = bf16pair(a0.x, a0.y); p.y = bf16pair(a0.z, a0.w);
        *reinterpret_cast<uint2*>(&hidU[(size_t)(row0 + g     ) * 50 + u0]) = p;
        p.x = bf16pair(a1.x, a1.y); p.y = bf16pair(a1.z, a1.w);
        *reinterpret_cast<uint2*>(&hidU[(size_t)(row0 + g + 10) * 50 + u0]) = p;
        p.x = bf16pair(a2.x, a2.y); p.y = bf16pair(a2.z, a2.w);
        *reinterpret_cast<uint2*>(&hidU[(size_t)(row0 + g + 20) * 50 + u0]) = p;
        p.x = bf16pair(a3.x, a3.y); p.y = bf16pair(a3.z, a3.w);
        *reinterpret_cast<uint2*>(&hidU[(size_t)(row0 + g + 30) * 50 + u0]) = p;
    }
}

// ---------------- bin1: edges -> 98 super-buckets of 512 nodes ------------
__global__ __launch_bounds__(256) void srgnn_bin1(
    const int* __restrict__ esrc, const int* __restrict__ edst,
    const float* __restrict__ ew, int* __restrict__ gcur1,
    int* __restrict__ ovfc, int4* __restrict__ ovf, uint2* __restrict__ bkt1)
{
    __shared__ int hist[SB_COUNT];
    __shared__ int lcur[SB_COUNT];
    const int t = threadIdx.x;
    const int e0 = blockIdx.x * EPB1;

    for (int i = t; i < SB_COUNT; i += 256) hist[i] = 0;
    __syncthreads();

    int d[8];
    #pragma unroll
    for (int k = 0; k < 8; ++k) {
        const int e = e0 + t + k * 256;
        d[k] = (e < N_EDGES) ? edst[e] : -1;
        if (d[k] >= 0) atomicAdd(&hist[d[k] >> 9], 1);
    }
    __syncthreads();
    for (int i = t; i < SB_COUNT; i += 256)
        if (hist[i]) lcur[i] = atomicAdd(&gcur1[i], hist[i]);
    __syncthreads();
    #pragma unroll
    for (int k = 0; k < 8; ++k) {
        if (d[k] >= 0) {
            const int e = e0 + t + k * 256;
            const int s = esrc[e];
            const float w = ew[e];
            const int sb = d[k] >> 9;
            const int pos = atomicAdd(&lcur[sb], 1);
            if (pos < CAP1) {
                bkt1[(size_t)sb * CAP1 + pos] =
                    make_uint2((unsigned)s | bf16hi(w), (unsigned)d[k]);
            } else {
                const int op = atomicAdd(ovfc, 1);
                if (op < OVF_CAP) ovf[op] = make_int4(d[k], s, __float_as_int(w), 0);
            }
        }
    }
}

// ---------------- bin2: 8 blocks per super-bucket -> final buckets --------
__global__ __launch_bounds__(256) void srgnn_bin2(
    const int* __restrict__ gcur1, const uint2* __restrict__ bkt1,
    int* __restrict__ cnt2, int* __restrict__ ovfc, int4* __restrict__ ovf,
    uint2* __restrict__ bkt2)
{
    __shared__ int histr[8][16];   // replicated local hist
    __shared__ int cur[16];        // global-reserved cursors
    const int t = threadIdx.x;
    const int sb = blockIdx.x >> 3;
    const int chunk = blockIdx.x & 7;
    const int rep = t & 7;

    int cnt = gcur1[sb];
    if (cnt > CAP1) cnt = CAP1;
    const int clen = (cnt + SPLIT2 - 1) >> 3;
    const int i0 = chunk * clen;
    int i1 = i0 + clen;
    if (i1 > cnt) i1 = cnt;

    if (t < 128) histr[t >> 4][t & 15] = 0;
    __syncthreads();

    for (int i = i0 + t; i < i1; i += 256) {
        const uint2 r = bkt1[(size_t)sb * CAP1 + i];
        atomicAdd(&histr[rep][(r.y >> 5) & 15], 1);
    }
    __syncthreads();

    if (t < 16) {
        int tot = 0;
        #pragma unroll
        for (int r = 0; r < 8; ++r) tot += histr[r][t];
        cur[t] = tot ? atomicAdd(&cnt2[sb * 16 + t], tot) : 0;
    }
    __syncthreads();

    for (int i = i0 + t; i < i1; i += 256) {
        const uint2 r = bkt1[(size_t)sb * CAP1 + i];
        const int j = (r.y >> 5) & 15;
        const int pos = atomicAdd(&cur[j], 1);
        if (pos < CAPB) {
            bkt2[(size_t)(sb * 16 + j) * CAPB + pos] = r;
        } else {
            const int op = atomicAdd(ovfc, 1);
            if (op < OVF_CAP)
                ovf[op] = make_int4((int)r.y, (int)(r.x & 0xFFFFu),
                                    (int)(r.x & 0xFFFF0000u), 0);
        }
    }
}

// ---------------- aggregate: block per 32-node bucket, LDS counting sort --
__global__ __launch_bounds__(256) void srgnn_agg_s32(
    const unsigned* __restrict__ hidU, const int* __restrict__ cnt2,
    const uint2* __restrict__ bkt2, const int* __restrict__ ovfc,
    const int4* __restrict__ ovf, float* __restrict__ out)
{
    __shared__ uint2    recs[CAPB];     // 6144 B
    __shared__ unsigned srt[CAPB];      // 3072 B
    __shared__ int nh[32], sc[32], cur[32];

    const int t = threadIdx.x;
    const int bq = blockIdx.x;
    int cntb = cnt2[bq];
    if (cntb > CAPB) cntb = CAPB;

    if (t < 32) nh[t] = 0;
    __syncthreads();
    for (int i = t; i < cntb; i += 256) {
        const uint2 r = bkt2[(size_t)bq * CAPB + i];
        recs[i] = r;
        atomicAdd(&nh[r.y & 31], 1);
    }
    __syncthreads();
    if (t < 32) sc[t] = nh[t];
    __syncthreads();
    for (int ofs = 1; ofs < 32; ofs <<= 1) {         // Hillis-Steele inclusive
        int a = 0;
        if (t < 32 && t >= ofs) a = sc[t - ofs];
        __syncthreads();
        if (t < 32) sc[t] += a;
        __syncthreads();
    }
    if (t < 32) cur[t] = sc[t] - nh[t];
    __syncthreads();
    for (int i = t; i < cntb; i += 256) {
        const uint2 r = recs[i];
        const int pos = atomicAdd(&cur[r.y & 31], 1);
        srt[pos] = r.x;                              // src | bf16(w)<<16
    }
    __syncthreads();

    int oc = *ovfc;                                  // ~always 0
    if (oc > OVF_CAP) oc = OVF_CAP;
    const int lane = t & 63;
    const int wid  = t >> 6;                         // 4 waves
    const bool active = (lane < 50);

    for (int q = 0; q < 8; ++q) {
        const int n  = wid * 8 + q;                  // 4 waves x 8 = 32 nodes
        const int s1 = sc[n];
        const int s0 = s1 - nh[n];
        float2 acc = make_float2(0.f, 0.f);

        int p = s0;
        for (; p + 8 <= s1; p += 8) {                // 8-deep MLP
            unsigned r[8], h[8];
            #pragma unroll
            for (int j = 0; j < 8; ++j) r[j] = srt[p + j];
            if (active) {
                #pragma unroll
                for (int j = 0; j < 8; ++j)
                    h[j] = hidU[(size_t)(r[j] & 0xFFFFu) * 50 + lane];
                #pragma unroll
                for (int j = 0; j < 8; ++j) {
                    const float wj = __uint_as_float(r[j] & 0xFFFF0000u);
                    acc.x += wj * __uint_as_float(h[j] << 16);
                    acc.y += wj * __uint_as_float(h[j] & 0xFFFF0000u);
                }
            }
        }
        for (; p < s1; ++p) {
            const unsigned r = srt[p];
            const float wi = __uint_as_float(r & 0xFFFF0000u);
            if (active) {
                const unsigned h = hidU[(size_t)(r & 0xFFFFu) * 50 + lane];
                acc.x += wi * __uint_as_float(h << 16);
                acc.y += wi * __uint_as_float(h & 0xFFFF0000u);
            }
        }

        const int ng = bq * 32 + n;
        if (oc > 0) {                                // ultra-rare overflow scan
            for (int i = 0; i < oc; ++i) {
                const int4 v = ovf[i];
                if (v.x == ng && active) {
                    const unsigned h = hidU[(size_t)v.y * 50 + lane];
                    const float wi = __uint_as_float((unsigned)v.z);
                    acc.x += wi * __uint_as_float(h << 16);
                    acc.y += wi * __uint_as_float(h & 0xFFFF0000u);
                }
            }
        }
        if (ng < N_NODES && active)
            *reinterpret_cast<float2*>(&out[(size_t)ng * DIM + 2 * lane]) = acc;
    }
}

// ---------------- fallback (atomic scatter, needs only 20MB ws) ----------
__global__ __launch_bounds__(256) void srgnn_gemm_bias(
    const float* __restrict__ x, const float* __restrict__ W,
    const float* __restrict__ b, float* __restrict__ hidden)
{
    __shared__ float Wt[DIM][DIM + 4];
    __shared__ float bs[DIM];
    __shared__ float xs[8][DIM];
    const int t = threadIdx.x;
    for (int i = t; i < DIM * DIM; i += 256) {
        int c = i / DIM, k = i - c * DIM;
        Wt[k][c] = W[i];
    }
    if (t < DIM) bs[t] = b[t];
    const int row0 = blockIdx.x * 8;
    for (int i = t; i < 8 * DIM; i += 256) {
        int r = i / DIM, k = i - r * DIM;
        int row = row0 + r;
        xs[r][k] = (row < N_NODES) ? x[row * DIM + k] : 0.0f;
    }
    __syncthreads();
    if (t < 200) {
        const int r  = t / 25;
        const int c4 = (t - r * 25) * 4;
        float acc0 = bs[c4 + 0], acc1 = bs[c4 + 1], acc2 = bs[c4 + 2], acc3 = bs[c4 + 3];
        for (int k = 0; k < DIM; ++k) {
            const float xv = xs[r][k];
            const float4 wv = *reinterpret_cast<const float4*>(&Wt[k][c4]);
            acc0 += xv * wv.x; acc1 += xv * wv.y; acc2 += xv * wv.z; acc3 += xv * wv.w;
        }
        const int row = row0 + r;
        if (row < N_NODES)
            *reinterpret_cast<float4*>(&hidden[row * DIM + c4]) =
                make_float4(acc0, acc1, acc2, acc3);
    }
}

__global__ __launch_bounds__(256) void srgnn_scatter_atomic(
    const float* __restrict__ hidden, const int* __restrict__ esrc,
    const int* __restrict__ edst, const float* __restrict__ ew,
    float* __restrict__ out)
{
    const unsigned gid = blockIdx.x * 256u + threadIdx.x;
    const unsigned e = gid / 25u;
    const unsigned j = gid - e * 25u;
    if (e >= N_EDGES) return;
    const int   s  = esrc[e];
    const int   d  = edst[e];
    const float wt = ew[e];
    const float4 h = *reinterpret_cast<const float4*>(&hidden[(size_t)s * DIM + j * 4]);
    float* op = &out[(size_t)d * DIM + j * 4];
    atomicAdd(op + 0, h.x * wt);
    atomicAdd(op + 1, h.y * wt);
    atomicAdd(op + 2, h.z * wt);
    atomicAdd(op + 3, h.w * wt);
}

extern "C" void kernel_launch(void* const* d_in, const int* in_sizes, int n_in,
                              void* d_out, int out_size, void* d_ws, size_t ws_size,
                              hipStream_t stream) {
    const float* x    = (const float*)d_in[0];
    const int*   esrc = (const int*)  d_in[1];
    const int*   edst = (const int*)  d_in[2];
    const float* ew   = (const float*)d_in[3];
    const float* W    = (const float*)d_in[4];
    const float* b    = (const float*)d_in[5];
    float* out = (float*)d_out;

    char* ws = (char*)d_ws;

    if (ws_size >= WS_NEED) {
        unsigned* hidU  = (unsigned*)(ws + HIDB_OFF);
        int*      gcur1 = (int*)     (ws + G1_OFF);
        int*      ovfc  = (int*)     (ws + OVFC_OFF);
        int*      cnt2  = (int*)     (ws + CNT2_OFF);
        int4*     ovf   = (int4*)    (ws + OVF_OFF);
        uint2*    bkt1  = (uint2*)   (ws + BKT1_OFF);
        uint2*    bkt2  = (uint2*)   (ws + BKT2_OFF);
        float*    Wt    = (float*)   (ws + WT_OFF);

        // transpose W + zero control buffers
        srgnn_transpose<<<(DIM * DIM + 255) / 256, 256, 0, stream>>>(
            W, Wt, gcur1, cnt2, ovfc);
        // GEMM with LDS-resident Wt
        srgnn_gemm3<<<GEMM_BLOCKS, 256, 0, stream>>>(x, Wt, b, hidU);
        // bin1: edges -> 98 super-buckets (contiguous runs)
        srgnn_bin1<<<BIN1_BLOCKS, 256, 0, stream>>>(
            esrc, edst, ew, gcur1, ovfc, ovf, bkt1);
        // bin2: 8 blocks/super-bucket -> 32-node buckets (long runs)
        srgnn_bin2<<<SB_COUNT * SPLIT2, 256, 0, stream>>>(
            gcur1, bkt1, cnt2, ovfc, ovf, bkt2);
        // block-per-bucket LDS sort + aggregate
        srgnn_agg_s32<<<NB, 256, 0, stream>>>(hidU, cnt2, bkt2, ovfc, ovf, out);
    } else {
        // fallback: atomic scatter
        float* hidden = (float*)ws;
        hipMemsetAsync(d_out, 0, (size_t)out_size * sizeof(float), stream);
        const int gemm_blocks = (N_NODES + 7) / 8;
        srgnn_gemm_bias<<<gemm_blocks, 256, 0, stream>>>(x, W, b, hidden);
        const long long work = (long long)N_EDGES * 25;
        const int scat_blocks = (int)((work + 255) / 256);
        srgnn_scatter_atomic<<<scat_blocks, 256, 0, stream>>>(hidden, esrc, edst, ew, out);
    }
}

// Round 15
// 72.256 us; speedup vs baseline: 1.7273x; 1.3048x over previous
//
#include <hip/hip_runtime.h>

#define N_NODES 50000
#define N_EDGES 800000
#define DIM 100

#define NB      1563        // buckets of 32 nodes: ceil(50000/32)
#define CAPB    768         // records per bucket region (mean 512, +11 sigma)
#define OVF_CAP 4096
#define EPB     8192        // edges per bin block
#define BIN_BLOCKS  98      // ceil(800000 / 8192)
#define GEMM_BLOCKS 625     // 50000 / 80
#define ROWS_PB 80          // gemm rows per (512-thread) block

// ---------------- workspace layout (bytes) ----------------
#define HIDB_OFF  0u            // bf16 hidden, packed uint[50000*50]   10,000,000
#define GCUR_OFF  10000000u     // int gcur[1563]                            6,256
#define OVFC_OFF  10006256u     // int ovf_cnt (+pad)                           16
#define OVF_OFF   10006272u     // int4 ovf[4096]                           65,536
#define BKT2_OFF  10071808u     // uint2 bkt2[1563*768] (128B-aligned)   9,603,072
#define WT_OFF    19674880u     // float Wt[100*100]                        40,000
#define WS_NEED   19714880u

// float->bf16 RNE helpers
__device__ inline unsigned bf16hi(float v) {            // bf16 in HIGH 16 bits
    unsigned u = __float_as_uint(v);
    u += 0x7FFFu + ((u >> 16) & 1u);
    return u & 0xFFFF0000u;
}
__device__ inline unsigned bf16pair(float lo, float hi) {
    unsigned ulo = __float_as_uint(lo); ulo += 0x7FFFu + ((ulo >> 16) & 1u);
    unsigned uhi = __float_as_uint(hi); uhi += 0x7FFFu + ((uhi >> 16) & 1u);
    return (ulo >> 16) | (uhi & 0xFFFF0000u);
}

// ---------------- transpose + control-buffer zeroing ----------------
__global__ __launch_bounds__(256) void srgnn_transpose(
    const float* __restrict__ W, float* __restrict__ Wt,
    int* __restrict__ gcur, int* __restrict__ ovfc)
{
    const unsigned i = blockIdx.x * 256u + threadIdx.x;
    if (i < DIM * DIM) {
        const int c = i / DIM, k = i - c * DIM;
        Wt[k * DIM + c] = W[i];
    }
    if (i < NB) gcur[i] = 0;
    if (i == 0) *ovfc = 0;
}

// ---------------- fused bin + GEMM (bin FIRST: bid<98) --------------------
// bin role: R9's proven single-pass bucket scatter (8192 edges -> 1563
// 32-node buckets via LDS hist + one gcur atomic per (block,bucket) run).
// gemm role: hidden(bf16) = x @ W^T + b with Wt AND xs LDS-resident
// (72KB -> 2 blocks/CU = 16 waves/CU): the inner loop touches no global
// memory and is FMA-bound (16 FMA vs ~4.5cyc LDS per k-iter). R9's
// global-Wt version thrashed L1 (40KB > 32KB) -> VALUBusy 27%, ~45us.
__global__ __launch_bounds__(512) void srgnn_gemm_bin(
    const float* __restrict__ x, const float* __restrict__ Wtg,
    const float* __restrict__ b, unsigned* __restrict__ hidU,
    const int* __restrict__ esrc, const int* __restrict__ edst,
    const float* __restrict__ ew, int* __restrict__ gcur,
    int* __restrict__ ovfc, int4* __restrict__ ovf, uint2* __restrict__ bkt2)
{
    __shared__ __align__(16) char smem[72000];
    const int t = threadIdx.x;

    if (blockIdx.x < BIN_BLOCKS) {
        // ---------------- bin part (starts at t=0, hides under gemm) -----
        int* hist = (int*)smem;                      // NB ints
        int* lcur = hist + NB;                       // NB ints (12504 B)
        const int e0 = blockIdx.x * EPB;

        for (int i = t; i < NB; i += 512) hist[i] = 0;
        __syncthreads();

        int d[16];
        #pragma unroll
        for (int k = 0; k < 16; ++k) {
            const int e = e0 + t + k * 512;
            d[k] = (e < N_EDGES) ? edst[e] : -1;
            if (d[k] >= 0) atomicAdd(&hist[d[k] >> 5], 1);
        }
        __syncthreads();
        for (int i = t; i < NB; i += 512)
            if (hist[i]) lcur[i] = atomicAdd(&gcur[i], hist[i]);
        __syncthreads();
        #pragma unroll
        for (int k = 0; k < 16; ++k) {
            if (d[k] >= 0) {
                const int e = e0 + t + k * 512;
                const int s = esrc[e];
                const float w = ew[e];
                const int bq = d[k] >> 5;
                const int pos = atomicAdd(&lcur[bq], 1);
                if (pos < CAPB) {
                    bkt2[(size_t)bq * CAPB + pos] =
                        make_uint2((unsigned)s | bf16hi(w), (unsigned)d[k]);
                } else {
                    const int op = atomicAdd(ovfc, 1);
                    if (op < OVF_CAP) ovf[op] = make_int4(d[k], s, __float_as_int(w), 0);
                }
            }
        }
    } else {
        // ---------------- GEMM part ----------------
        float (*Wt)[DIM] = (float (*)[DIM])smem;             // 40000 B
        float (*xs)[DIM] = (float (*)[DIM])(smem + 40000);   // 32000 B
        const int row0 = (blockIdx.x - BIN_BLOCKS) * ROWS_PB;

        for (int i = t; i < 2500; i += 512) {
            const float4 v = *reinterpret_cast<const float4*>(&Wtg[i * 4]);
            *reinterpret_cast<float4*>(&Wt[0][0] + i * 4) = v;
        }
        for (int i = t; i < ROWS_PB * 25; i += 512) {
            const int r = i / 25, c4 = (i - r * 25) * 4;
            const float4 v = *reinterpret_cast<const float4*>(
                &x[(size_t)(row0 + r) * DIM + c4]);
            *reinterpret_cast<float4*>(&xs[r][c4]) = v;
        }
        __syncthreads();

        if (t < 500) {
            const int g  = t / 25;            // row group 0..19
            const int c4 = (t - g * 25) * 4;  // col chunk
            const float4 bv = *reinterpret_cast<const float4*>(&b[c4]);
            float4 a0 = bv, a1 = bv, a2 = bv, a3 = bv;

            #pragma unroll 4
            for (int k = 0; k < DIM; ++k) {
                const float4 wv = *reinterpret_cast<const float4*>(&Wt[k][c4]);
                const float x0 = xs[g     ][k];
                const float x1 = xs[g + 20][k];
                const float x2 = xs[g + 40][k];
                const float x3 = xs[g + 60][k];
                a0.x += x0 * wv.x; a0.y += x0 * wv.y; a0.z += x0 * wv.z; a0.w += x0 * wv.w;
                a1.x += x1 * wv.x; a1.y += x1 * wv.y; a1.z += x1 * wv.z; a1.w += x1 * wv.w;
                a2.x += x2 * wv.x; a2.y += x2 * wv.y; a2.z += x2 * wv.z; a2.w += x2 * wv.w;
                a3.x += x3 * wv.x; a3.y += x3 * wv.y; a3.z += x3 * wv.z; a3.w += x3 * wv.w;
            }
            const int u0 = c4 >> 1;           // uint index within row
            uint2 p;
            p.x = bf16pair(a0.x, a0.y); p.y = bf16pair(a0.z, a0.w);
            *reinterpret_cast<uint2*>(&hidU[(size_t)(row0 + g     ) * 50 + u0]) = p;
            p.x = bf16pair(a1.x, a1.y); p.y = bf16pair(a1.z, a1.w);
            *reinterpret_cast<uint2*>(&hidU[(size_t)(row0 + g + 20) * 50 + u0]) = p;
            p.x = bf16pair(a2.x, a2.y); p.y = bf16pair(a2.z, a2.w);
            *reinterpret_cast<uint2*>(&hidU[(size_t)(row0 + g + 40) * 50 + u0]) = p;
            p.x = bf16pair(a3.x, a3.y); p.y = bf16pair(a3.z, a3.w);
            *reinterpret_cast<uint2*>(&hidU[(size_t)(row0 + g + 60) * 50 + u0]) = p;
        }
    }
}

// ---------------- aggregate: block per 32-node bucket, LDS counting sort --
__global__ __launch_bounds__(256) void srgnn_agg_s32(
    const unsigned* __restrict__ hidU, const int* __restrict__ gcur,
    const uint2* __restrict__ bkt2, const int* __restrict__ ovfc,
    const int4* __restrict__ ovf, float* __restrict__ out)
{
    __shared__ uint2    recs[CAPB];     // 6144 B
    __shared__ unsigned srt[CAPB];      // 3072 B
    __shared__ int nh[32], sc[32], cur[32];

    const int t = threadIdx.x;
    const int bq = blockIdx.x;
    int cntb = gcur[bq];
    if (cntb > CAPB) cntb = CAPB;

    if (t < 32) nh[t] = 0;
    __syncthreads();
    for (int i = t; i < cntb; i += 256) {
        const uint2 r = bkt2[(size_t)bq * CAPB + i];
        recs[i] = r;
        atomicAdd(&nh[r.y & 31], 1);
    }
    __syncthreads();
    if (t < 32) sc[t] = nh[t];
    __syncthreads();
    for (int ofs = 1; ofs < 32; ofs <<= 1) {         // Hillis-Steele inclusive
        int a = 0;
        if (t < 32 && t >= ofs) a = sc[t - ofs];
        __syncthreads();
        if (t < 32) sc[t] += a;
        __syncthreads();
    }
    if (t < 32) cur[t] = sc[t] - nh[t];
    __syncthreads();
    for (int i = t; i < cntb; i += 256) {
        const uint2 r = recs[i];
        const int pos = atomicAdd(&cur[r.y & 31], 1);
        srt[pos] = r.x;                              // src | bf16(w)<<16
    }
    __syncthreads();

    int oc = *ovfc;                                  // ~always 0
    if (oc > OVF_CAP) oc = OVF_CAP;
    const int lane = t & 63;
    const int wid  = t >> 6;                         // 4 waves
    const bool active = (lane < 50);

    for (int q = 0; q < 8; ++q) {
        const int n  = wid * 8 + q;                  // 4 waves x 8 = 32 nodes
        const int s1 = sc[n];
        const int s0 = s1 - nh[n];
        float2 acc = make_float2(0.f, 0.f);

        int p = s0;
        for (; p + 8 <= s1; p += 8) {                // 8-deep MLP
            unsigned r[8], h[8];
            #pragma unroll
            for (int j = 0; j < 8; ++j) r[j] = srt[p + j];
            if (active) {
                #pragma unroll
                for (int j = 0; j < 8; ++j)
                    h[j] = hidU[(size_t)(r[j] & 0xFFFFu) * 50 + lane];
                #pragma unroll
                for (int j = 0; j < 8; ++j) {
                    const float wj = __uint_as_float(r[j] & 0xFFFF0000u);
                    acc.x += wj * __uint_as_float(h[j] << 16);
                    acc.y += wj * __uint_as_float(h[j] & 0xFFFF0000u);
                }
            }
        }
        for (; p < s1; ++p) {
            const unsigned r = srt[p];
            const float wi = __uint_as_float(r & 0xFFFF0000u);
            if (active) {
                const unsigned h = hidU[(size_t)(r & 0xFFFFu) * 50 + lane];
                acc.x += wi * __uint_as_float(h << 16);
                acc.y += wi * __uint_as_float(h & 0xFFFF0000u);
            }
        }

        const int ng = bq * 32 + n;
        if (oc > 0) {                                // ultra-rare overflow scan
            for (int i = 0; i < oc; ++i) {
                const int4 v = ovf[i];
                if (v.x == ng && active) {
                    const unsigned h = hidU[(size_t)v.y * 50 + lane];
                    const float wi = __int_as_float(v.z);
                    acc.x += wi * __uint_as_float(h << 16);
                    acc.y += wi * __uint_as_float(h & 0xFFFF0000u);
                }
            }
        }
        if (ng < N_NODES && active)
            *reinterpret_cast<float2*>(&out[(size_t)ng * DIM + 2 * lane]) = acc;
    }
}

// ---------------- fallback (atomic scatter, needs only 20MB ws) ----------
__global__ __launch_bounds__(256) void srgnn_gemm_bias(
    const float* __restrict__ x, const float* __restrict__ W,
    const float* __restrict__ b, float* __restrict__ hidden)
{
    __shared__ float Wt[DIM][DIM + 4];
    __shared__ float bs[DIM];
    __shared__ float xs[8][DIM];
    const int t = threadIdx.x;
    for (int i = t; i < DIM * DIM; i += 256) {
        int c = i / DIM, k = i - c * DIM;
        Wt[k][c] = W[i];
    }
    if (t < DIM) bs[t] = b[t];
    const int row0 = blockIdx.x * 8;
    for (int i = t; i < 8 * DIM; i += 256) {
        int r = i / DIM, k = i - r * DIM;
        int row = row0 + r;
        xs[r][k] = (row < N_NODES) ? x[row * DIM + k] : 0.0f;
    }
    __syncthreads();
    if (t < 200) {
        const int r  = t / 25;
        const int c4 = (t - r * 25) * 4;
        float acc0 = bs[c4 + 0], acc1 = bs[c4 + 1], acc2 = bs[c4 + 2], acc3 = bs[c4 + 3];
        for (int k = 0; k < DIM; ++k) {
            const float xv = xs[r][k];
            const float4 wv = *reinterpret_cast<const float4*>(&Wt[k][c4]);
            acc0 += xv * wv.x; acc1 += xv * wv.y; acc2 += xv * wv.z; acc3 += xv * wv.w;
        }
        const int row = row0 + r;
        if (row < N_NODES)
            *reinterpret_cast<float4*>(&hidden[row * DIM + c4]) =
                make_float4(acc0, acc1, acc2, acc3);
    }
}

__global__ __launch_bounds__(256) void srgnn_scatter_atomic(
    const float* __restrict__ hidden, const int* __restrict__ esrc,
    const int* __restrict__ edst, const float* __restrict__ ew,
    float* __restrict__ out)
{
    const unsigned gid = blockIdx.x * 256u + threadIdx.x;
    const unsigned e = gid / 25u;
    const unsigned j = gid - e * 25u;
    if (e >= N_EDGES) return;
    const int   s  = esrc[e];
    const int   d  = edst[e];
    const float wt = ew[e];
    const float4 h = *reinterpret_cast<const float4*>(&hidden[(size_t)s * DIM + j * 4]);
    float* op = &out[(size_t)d * DIM + j * 4];
    atomicAdd(op + 0, h.x * wt);
    atomicAdd(op + 1, h.y * wt);
    atomicAdd(op + 2, h.z * wt);
    atomicAdd(op + 3, h.w * wt);
}

extern "C" void kernel_launch(void* const* d_in, const int* in_sizes, int n_in,
                              void* d_out, int out_size, void* d_ws, size_t ws_size,
                              hipStream_t stream) {
    const float* x    = (const float*)d_in[0];
    const int*   esrc = (const int*)  d_in[1];
    const int*   edst = (const int*)  d_in[2];
    const float* ew   = (const float*)d_in[3];
    const float* W    = (const float*)d_in[4];
    const float* b    = (const float*)d_in[5];
    float* out = (float*)d_out;

    char* ws = (char*)d_ws;

    if (ws_size >= WS_NEED) {
        unsigned* hidU = (unsigned*)(ws + HIDB_OFF);
        int*      gcur = (int*)     (ws + GCUR_OFF);
        int*      ovfc = (int*)     (ws + OVFC_OFF);
        int4*     ovf  = (int4*)    (ws + OVF_OFF);
        uint2*    bkt2 = (uint2*)   (ws + BKT2_OFF);
        float*    Wt   = (float*)   (ws + WT_OFF);

        // transpose W + zero control buffers (one dispatch)
        srgnn_transpose<<<(DIM * DIM + 255) / 256, 256, 0, stream>>>(W, Wt, gcur, ovfc);
        // fused: bin (98 blocks, FIRST) + GEMM w/ LDS-resident Wt (625 blocks)
        srgnn_gemm_bin<<<BIN_BLOCKS + GEMM_BLOCKS, 512, 0, stream>>>(
            x, Wt, b, hidU, esrc, edst, ew, gcur, ovfc, ovf, bkt2);
        // block-per-bucket LDS sort + aggregate
        srgnn_agg_s32<<<NB, 256, 0, stream>>>(hidU, gcur, bkt2, ovfc, ovf, out);
    } else {
        // fallback: atomic scatter
        float* hidden = (float*)ws;
        hipMemsetAsync(d_out, 0, (size_t)out_size * sizeof(float), stream);
        const int gemm_blocks = (N_NODES + 7) / 8;
        srgnn_gemm_bias<<<gemm_blocks, 256, 0, stream>>>(x, W, b, hidden);
        const long long work = (long long)N_EDGES * 25;
        const int scat_blocks = (int)((work + 255) / 256);
        srgnn_scatter_atomic<<<scat_blocks, 256, 0, stream>>>(hidden, esrc, edst, ew, out);
    }
}